// Round 5
// baseline (470.678 us; speedup 1.0000x reference)
//
#include <hip/hip_runtime.h>

#define PP 8
#define ZD 16
#define H1C 128
#define H2C 512
#define CHC 224
#define NB 32768
#define EPSV 1e-5f

// header layout in d_ws (float offsets)
#define OFF_S1SUM 0
#define OFF_S1SQ  1024
#define OFF_SC1   2048
#define OFF_SH1   3072
#define OFF_S2SUM 4096
#define OFF_S2SQ  8192
#define OFF_SC2F  12288
#define OFF_SH2F  16384
#define OFF_B8P   20480
#define OFF_TTH   22528
#define HDR_BYTES 131072

typedef __attribute__((ext_vector_type(8))) short s16x8;
typedef __attribute__((ext_vector_type(4))) float f32x4;

__device__ __forceinline__ unsigned short f2bf(float f) {
  unsigned int u = __float_as_uint(f);
  unsigned int r = (u + 0x7fffu + ((u >> 16) & 1u)) >> 16;
  return (unsigned short)r;
}
__device__ __forceinline__ float bf2f(unsigned short h) {
  return __uint_as_float((unsigned int)h << 16);
}

// async global->LDS, 16B per lane; lds dest is wave-uniform base + lane*16
#define GLL16(g, l)                                                        \
  __builtin_amdgcn_global_load_lds(                                        \
      (const __attribute__((address_space(1))) unsigned int*)(g),          \
      (__attribute__((address_space(3))) unsigned int*)(l), 16, 0, 0)

// ---------------------------------------------------------------------------
// kw: convert W7 -> W7b bf16, slot-swizzled by (c&7) within each 64-k chunk.
__global__ __launch_bounds__(256) void kw_conv(const float* __restrict__ W7,
                                               unsigned short* __restrict__ W7b) {
  int i8 = (blockIdx.x * 256 + threadIdx.x) * 8;
  int k = i8 & (H1C - 1);
  int c = (i8 >> 7) & (H2C - 1);
  int base = i8 - k;
  int kd = (k & ~63) + ((((k >> 3) & 7) ^ (c & 7)) << 3);
  float4 v0 = *(const float4*)&W7[i8];
  float4 v1 = *(const float4*)&W7[i8 + 4];
  s16x8 o;
  o[0] = (short)f2bf(v0.x); o[1] = (short)f2bf(v0.y);
  o[2] = (short)f2bf(v0.z); o[3] = (short)f2bf(v0.w);
  o[4] = (short)f2bf(v1.x); o[5] = (short)f2bf(v1.y);
  o[6] = (short)f2bf(v1.z); o[7] = (short)f2bf(v1.w);
  *(s16x8*)&W7b[base + kd] = o;
}

// ---------------------------------------------------------------------------
// K1: BN1 stats (fp32 h1 recompute from z, K=16)
__global__ __launch_bounds__(128) void k1_stats1(
    const float* __restrict__ z, const float* __restrict__ W6,
    const float* __restrict__ b6, float* __restrict__ hdr) {
  __shared__ float zs[512 * ZD];
  __shared__ float w6s[H1C * ZD];
  const int t = threadIdx.x;
  const int p = blockIdx.y;
  const int n0 = blockIdx.x * 512;
  for (int i = t; i < H1C * ZD; i += 128) w6s[i] = W6[(size_t)p * (H1C * ZD) + i];
  for (int i = t; i < 512 * ZD; i += 128) zs[i] = z[(size_t)n0 * ZD + i];
  __syncthreads();
  float wr_[ZD];
#pragma unroll
  for (int q = 0; q < ZD; ++q) wr_[q] = w6s[t * ZD + q];
  float bb = b6[p * H1C + t];
  float s = 0.f, sq = 0.f;
  for (int n = 0; n < 512; ++n) {
    float v = bb;
    const float4* zp = (const float4*)&zs[n * ZD];
#pragma unroll
    for (int q4 = 0; q4 < 4; ++q4) {
      float4 zv = zp[q4];
      v = fmaf(zv.x, wr_[q4 * 4 + 0], v);
      v = fmaf(zv.y, wr_[q4 * 4 + 1], v);
      v = fmaf(zv.z, wr_[q4 * 4 + 2], v);
      v = fmaf(zv.w, wr_[q4 * 4 + 3], v);
    }
    s += v;
    sq = fmaf(v, v, sq);
  }
  atomicAdd(&hdr[OFF_S1SUM + p * H1C + t], s);
  atomicAdd(&hdr[OFF_S1SQ + p * H1C + t], sq);
}

__global__ void k1_fin(const float* __restrict__ g6,
                       const float* __restrict__ be6, float* __restrict__ hdr) {
  int j = blockIdx.x * 256 + threadIdx.x;
  if (j >= PP * H1C) return;
  float mu = hdr[OFF_S1SUM + j] * (1.f / NB);
  float var = fmaxf(hdr[OFF_S1SQ + j] * (1.f / NB) - mu * mu, 0.f);
  float sc = g6[j] * rsqrtf(var + EPSV);
  hdr[OFF_SC1 + j] = sc;
  hdr[OFF_SH1 + j] = be6[j] - mu * sc;
}

// ---------------------------------------------------------------------------
// K1c: h1act = relu(affine(z*W6^T)) bf16 [p][n][128], slot-swizzled by n&7
__global__ __launch_bounds__(256) void k1c_act1(
    const float* __restrict__ z, const float* __restrict__ W6,
    const float* __restrict__ b6, const float* __restrict__ hdr,
    unsigned short* __restrict__ h1a) {
  __shared__ float w6s[H1C * 20];
  __shared__ float cb[H1C], cs[H1C], ch[H1C];
  const int t = threadIdx.x;
  const int p = blockIdx.y;
  const int n0 = blockIdx.x * 128;
  for (int i = t; i < H1C * ZD; i += 256)
    w6s[(i >> 4) * 20 + (i & 15)] = W6[(size_t)p * (H1C * ZD) + i];
  if (t < H1C) {
    cb[t] = b6[p * H1C + t];
    cs[t] = hdr[OFF_SC1 + p * H1C + t];
    ch[t] = hdr[OFF_SH1 + p * H1C + t];
  }
  __syncthreads();
  const int row = t >> 1;
  const int n = n0 + row;
  const int h0 = (t & 1) * 64;
  const float* zp = z + (size_t)n * ZD;
  float zr[ZD];
#pragma unroll
  for (int q = 0; q < ZD; ++q) zr[q] = zp[q];
  unsigned short* rowp = h1a + ((size_t)p * NB + n) * H1C;
  for (int hb = 0; hb < 64; hb += 8) {
    s16x8 o;
#pragma unroll
    for (int j = 0; j < 8; ++j) {
      int h = h0 + hb + j;
      float v = cb[h];
#pragma unroll
      for (int q4 = 0; q4 < 4; ++q4) {
        float4 wv = *(const float4*)&w6s[h * 20 + q4 * 4];
        v = fmaf(zr[q4 * 4 + 0], wv.x, v);
        v = fmaf(zr[q4 * 4 + 1], wv.y, v);
        v = fmaf(zr[q4 * 4 + 2], wv.z, v);
        v = fmaf(zr[q4 * 4 + 3], wv.w, v);
      }
      v = fmaxf(fmaf(v, cs[h], ch[h]), 0.f);
      o[j] = (short)f2bf(v);
    }
    int hbase = h0 + hb;
    int kd = (hbase & ~63) + ((((hbase >> 3) & 7) ^ (n & 7)) << 3);
    *(s16x8*)(rowp + kd) = o;
  }
}

// ---------------------------------------------------------------------------
// K2: bf16 MFMA GEMM (M=NB, N=512, K=128), fused bias + BN2 stats epilogue.
__global__ __launch_bounds__(256) void k2_gemm2(
    const unsigned short* __restrict__ h1a, const unsigned short* __restrict__ W7b,
    const float* __restrict__ b7, float* __restrict__ hdr,
    unsigned short* __restrict__ h2b, int p0) {
  __shared__ unsigned short Abuf[128 * 64];
  __shared__ unsigned short Bbuf[128 * 64];
  const int t = threadIdx.x;
  const int lane = t & 63;
  const int w = t >> 6, wr = w >> 1, wc = w & 1;
  const int pl = blockIdx.z, p = p0 + pl;
  const int n0 = blockIdx.x * 128;
  const int c0 = blockIdx.y * 128;

  const int srow = lane >> 3;
  const int ke = (lane & 7) * 8;
  const size_t abase = ((size_t)p * NB + n0) * H1C;
  const size_t bbase = ((size_t)p * H2C + c0) * H1C;

  f32x4 acc[4][4] = {};

  for (int kt = 0; kt < H1C / 64; ++kt) {
    __syncthreads();
#pragma unroll
    for (int c = 0; c < 4; ++c) {
      int row = (w * 4 + c) * 8 + srow;
      GLL16(h1a + abase + (size_t)row * H1C + kt * 64 + ke,
            (char*)Abuf + (w * 4 + c) * 1024);
      GLL16(W7b + bbase + (size_t)row * H1C + kt * 64 + ke,
            (char*)Bbuf + (w * 4 + c) * 1024);
    }
    __syncthreads();
    const int sw = lane & 7;
#pragma unroll
    for (int kk = 0; kk < 2; ++kk) {
      const int sl = kk * 4 + (lane >> 4);
      s16x8 af[4], bfv[4];
#pragma unroll
      for (int m = 0; m < 4; ++m)
        af[m] = *(const s16x8*)&Abuf[(wr * 64 + m * 16 + (lane & 15)) * 64 +
                                     ((sl ^ sw) << 3)];
#pragma unroll
      for (int n = 0; n < 4; ++n)
        bfv[n] = *(const s16x8*)&Bbuf[(wc * 64 + n * 16 + (lane & 15)) * 64 +
                                      ((sl ^ sw) << 3)];
#pragma unroll
      for (int m = 0; m < 4; ++m)
#pragma unroll
        for (int n = 0; n < 4; ++n)
          acc[m][n] = __builtin_amdgcn_mfma_f32_16x16x32_bf16(af[m], bfv[n],
                                                              acc[m][n], 0, 0, 0);
    }
  }

#pragma unroll
  for (int n = 0; n < 4; ++n) {
    const int col = c0 + wc * 64 + n * 16 + (lane & 15);
    const float bias = b7[p * H2C + col];
    float s = 0.f, q = 0.f;
#pragma unroll
    for (int m = 0; m < 4; ++m) {
      const int rowb = n0 + wr * 64 + m * 16 + (lane >> 4) * 4;
#pragma unroll
      for (int r = 0; r < 4; ++r) {
        float v = acc[m][n][r] + bias;
        unsigned short hb = f2bf(v);
        h2b[((size_t)pl * NB + rowb + r) * H2C + col] = hb;
        float vf = bf2f(hb);
        s += vf;
        q = fmaf(vf, vf, q);
      }
    }
    s += __shfl_xor(s, 16); q += __shfl_xor(q, 16);
    s += __shfl_xor(s, 32); q += __shfl_xor(q, 32);
    if ((lane >> 4) == 0) {
      atomicAdd(&hdr[OFF_S2SUM + p * H2C + col], s);
      atomicAdd(&hdr[OFF_S2SQ + p * H2C + col], q);
    }
  }
}

// K3fin: BN2 affine params -> flat sc, sh, and threshold t = -sh/sc
__global__ void k3_fin(const float* __restrict__ g7,
                       const float* __restrict__ be7, float* __restrict__ hdr,
                       int p0, int pg) {
  int idx = blockIdx.x * 256 + threadIdx.x;
  if (idx >= pg * H2C) return;
  int row = p0 * H2C + idx;
  float mu = hdr[OFF_S2SUM + row] * (1.f / NB);
  float var = fmaxf(hdr[OFF_S2SQ + row] * (1.f / NB) - mu * mu, 0.f);
  float sc = g7[row] * rsqrtf(var + EPSV);
  float sh = be7[row] - mu * sc;
  hdr[OFF_SC2F + row] = sc;
  hdr[OFF_SH2F + row] = sh;
  hdr[OFF_TTH + row] = -sh / sc;
}

// kfold_w: W8s[c,k] = bf16(W8[c,k] * sc[k]), slot-swizzled by (c&7)
__global__ __launch_bounds__(256) void kfold_w(const float* __restrict__ W8,
                                               const float* __restrict__ hdr,
                                               unsigned short* __restrict__ W8s,
                                               int p0) {
  int d = (blockIdx.x * 256 + threadIdx.x) * 8;  // within p-group
  int ks = d & (H2C - 1);
  int cc = d >> 9;
  int c = cc % CHC;
  int p = p0 + cc / CHC;
  int kl = (ks & ~63) + (((((ks >> 3) & 7)) ^ (c & 7)) << 3);
  const float* src = &W8[((size_t)p * CHC + c) * H2C + kl];
  const float* scp = &hdr[OFF_SC2F + p * H2C + kl];
  float4 v0 = *(const float4*)src, v1 = *(const float4*)(src + 4);
  float4 s0 = *(const float4*)scp, s1 = *(const float4*)(scp + 4);
  s16x8 o;
  o[0] = (short)f2bf(v0.x * s0.x); o[1] = (short)f2bf(v0.y * s0.y);
  o[2] = (short)f2bf(v0.z * s0.z); o[3] = (short)f2bf(v0.w * s0.w);
  o[4] = (short)f2bf(v1.x * s1.x); o[5] = (short)f2bf(v1.y * s1.y);
  o[6] = (short)f2bf(v1.z * s1.z); o[7] = (short)f2bf(v1.w * s1.w);
  *(s16x8*)&W8s[((size_t)p * CHC + c) * H2C + ks] = o;
}

// kfold_b: b8'[p,c] = b8[p,c] + sum_k W8[c,k]*sh[k]  (one wave per row)
__global__ __launch_bounds__(256) void kfold_b(const float* __restrict__ W8,
                                               const float* __restrict__ b8,
                                               float* __restrict__ hdr, int p0) {
  int gw = (blockIdx.x * 256 + threadIdx.x) >> 6;
  int lane = threadIdx.x & 63;
  int p = p0 + gw / CHC;
  int c = gw % CHC;
  const float* wrow = W8 + ((size_t)p * CHC + c) * H2C + lane * 8;
  const float* shp = hdr + OFF_SH2F + p * H2C + lane * 8;
  float s = 0.f;
  float4 a0 = *(const float4*)wrow, a1 = *(const float4*)(wrow + 4);
  float4 h0 = *(const float4*)shp, h1 = *(const float4*)(shp + 4);
  s = fmaf(a0.x, h0.x, s); s = fmaf(a0.y, h0.y, s);
  s = fmaf(a0.z, h0.z, s); s = fmaf(a0.w, h0.w, s);
  s = fmaf(a1.x, h1.x, s); s = fmaf(a1.y, h1.y, s);
  s = fmaf(a1.z, h1.z, s); s = fmaf(a1.w, h1.w, s);
  s += __shfl_xor(s, 1);  s += __shfl_xor(s, 2);  s += __shfl_xor(s, 4);
  s += __shfl_xor(s, 8);  s += __shfl_xor(s, 16); s += __shfl_xor(s, 32);
  if (lane == 0) hdr[OFF_B8P + p * CHC + c] = b8[p * CHC + c] + s;
}

// ---------------------------------------------------------------------------
// K4: bf16 MFMA GEMM (M=NB, N=224, K=512), 128x224 tile, 3 blocks/CU.
// A: reg-staged; transform = max(v, t_k) only (BN folded into W8s/b8').
__global__ __launch_bounds__(256, 3) void k4_gemm3(
    const unsigned short* __restrict__ h2b, const unsigned short* __restrict__ W8s,
    const float* __restrict__ hdr, float* __restrict__ out, int p0) {
  __shared__ unsigned short Abuf[128 * 64];  // 16KB, slot-swizzled by row&7
  __shared__ unsigned short Bbuf[224 * 64];  // 28KB, swizzled via global layout
  __shared__ float tb[H2C];                  // 2KB thresholds
  const int t = threadIdx.x;
  const int lane = t & 63;
  const int w = t >> 6, wr = w >> 1, wc = w & 1;
  const int pl = blockIdx.z, p = p0 + pl;
  const int n0 = blockIdx.x * 128;

  for (int i = t; i < H2C; i += 256) tb[i] = hdr[OFF_TTH + p * H2C + i];

  const int r = t >> 1;
  const int sb = (t & 1) * 4;
  const unsigned short* arow = h2b + ((size_t)pl * NB + n0 + r) * H2C + sb * 8;
  const int qrow = lane >> 3, qsl = lane & 7;

  f32x4 acc[4][7] = {};

  for (int kt = 0; kt < H2C / 64; ++kt) {
    __syncthreads();  // prev frag reads done; tb visible at kt=0
    // A raw load (64B/thread) for this kt
    s16x8 cur[4];
#pragma unroll
    for (int j = 0; j < 4; ++j)
      cur[j] = *(const s16x8*)(arow + kt * 64 + j * 8);
    // B staging: 28 one-KB blocks (8 rows x 64 k each); 4 waves x 7
#pragma unroll
    for (int c = 0; c < 7; ++c) {
      int qq = w * 7 + c;
      GLL16(W8s + ((size_t)p * CHC + qq * 8 + qrow) * H2C + kt * 64 + qsl * 8,
            (char*)Bbuf + qq * 1024);
    }
    // transform cur -> Abuf: A' = max(v, t_k); pack via v_cvt_pk_bf16_f32
#pragma unroll
    for (int j = 0; j < 4; ++j) {
      int kb = kt * 64 + sb * 8 + j * 8;
      f32x4 t0 = *(const f32x4*)&tb[kb];
      f32x4 t1 = *(const f32x4*)&tb[kb + 4];
      float m0 = fmaxf(bf2f((unsigned short)cur[j][0]), t0[0]);
      float m1 = fmaxf(bf2f((unsigned short)cur[j][1]), t0[1]);
      float m2 = fmaxf(bf2f((unsigned short)cur[j][2]), t0[2]);
      float m3 = fmaxf(bf2f((unsigned short)cur[j][3]), t0[3]);
      float m4 = fmaxf(bf2f((unsigned short)cur[j][4]), t1[0]);
      float m5 = fmaxf(bf2f((unsigned short)cur[j][5]), t1[1]);
      float m6 = fmaxf(bf2f((unsigned short)cur[j][6]), t1[2]);
      float m7 = fmaxf(bf2f((unsigned short)cur[j][7]), t1[3]);
      unsigned int w0, w1, w2, w3;
      asm("v_cvt_pk_bf16_f32 %0, %1, %2" : "=v"(w0) : "v"(m0), "v"(m1));
      asm("v_cvt_pk_bf16_f32 %0, %1, %2" : "=v"(w1) : "v"(m2), "v"(m3));
      asm("v_cvt_pk_bf16_f32 %0, %1, %2" : "=v"(w2) : "v"(m4), "v"(m5));
      asm("v_cvt_pk_bf16_f32 %0, %1, %2" : "=v"(w3) : "v"(m6), "v"(m7));
      uint4 o;
      o.x = w0; o.y = w1; o.z = w2; o.w = w3;
      int slot = (sb + j) ^ (r & 7);
      *(uint4*)((char*)Abuf + r * 128 + slot * 16) = o;
    }
    __syncthreads();
    const int sw = lane & 7;
#pragma unroll
    for (int kk = 0; kk < 2; ++kk) {
      const int sl = kk * 4 + (lane >> 4);
      s16x8 af[4], bfv[7];
#pragma unroll
      for (int m = 0; m < 4; ++m)
        af[m] = *(const s16x8*)&Abuf[(wr * 64 + m * 16 + (lane & 15)) * 64 +
                                     ((sl ^ sw) << 3)];
#pragma unroll
      for (int n = 0; n < 7; ++n)
        bfv[n] = *(const s16x8*)&Bbuf[(wc * 112 + n * 16 + (lane & 15)) * 64 +
                                      ((sl ^ sw) << 3)];
#pragma unroll
      for (int m = 0; m < 4; ++m)
#pragma unroll
        for (int n = 0; n < 7; ++n)
          acc[m][n] = __builtin_amdgcn_mfma_f32_16x16x32_bf16(af[m], bfv[n],
                                                              acc[m][n], 0, 0, 0);
    }
  }

#pragma unroll
  for (int n = 0; n < 7; ++n) {
    const int col = wc * 112 + n * 16 + (lane & 15);
    const float bias = hdr[OFF_B8P + p * CHC + col];
#pragma unroll
    for (int m = 0; m < 4; ++m) {
      const int rowb = n0 + wr * 64 + m * 16 + (lane >> 4) * 4;
#pragma unroll
      for (int rr = 0; rr < 4; ++rr) {
        float x = acc[m][n][rr] + bias;
        out[((size_t)(rowb + rr) * PP + p) * CHC + col] = 1.f / (1.f + __expf(-x));
      }
    }
  }
}

// ---------------------------------------------------------------------------
extern "C" void kernel_launch(void* const* d_in, const int* in_sizes, int n_in,
                              void* d_out, int out_size, void* d_ws,
                              size_t ws_size, hipStream_t stream) {
  (void)in_sizes; (void)n_in; (void)out_size;
  const float* z   = (const float*)d_in[0];
  const float* W6  = (const float*)d_in[1];
  const float* b6  = (const float*)d_in[2];
  const float* g6  = (const float*)d_in[3];
  const float* be6 = (const float*)d_in[4];
  const float* W7  = (const float*)d_in[5];
  const float* b7  = (const float*)d_in[6];
  const float* g7  = (const float*)d_in[7];
  const float* be7 = (const float*)d_in[8];
  const float* W8  = (const float*)d_in[9];
  const float* b8  = (const float*)d_in[10];
  float* out = (float*)d_out;
  float* hdr = (float*)d_ws;
  unsigned short* W7b = (unsigned short*)((char*)d_ws + HDR_BYTES);
  unsigned short* W8s = W7b + (size_t)PP * H2C * H1C;
  unsigned short* h1a = W8s + (size_t)PP * CHC * H2C;
  unsigned short* h2b = h1a + (size_t)PP * NB * H1C;

  size_t fixed = HDR_BYTES + 2 * ((size_t)PP * H2C * H1C + (size_t)PP * CHC * H2C +
                                  (size_t)PP * NB * H1C);
  size_t per_p = (size_t)NB * H2C * 2;
  size_t avail = ws_size > fixed ? ws_size - fixed : 0;
  int PG = (int)(avail / per_p);
  if (PG < 1) PG = 1;
  if (PG > PP) PG = PP;

  hipMemsetAsync(hdr + OFF_S1SUM, 0, 2048 * sizeof(float), stream);
  kw_conv<<<256, 256, 0, stream>>>(W7, W7b);
  k1_stats1<<<dim3(NB / 512, PP), 128, 0, stream>>>(z, W6, b6, hdr);
  k1_fin<<<4, 256, 0, stream>>>(g6, be6, hdr);
  k1c_act1<<<dim3(NB / 128, PP), 256, 0, stream>>>(z, W6, b6, hdr, h1a);

  for (int p0 = 0; p0 < PP; p0 += PG) {
    int pg = (PP - p0 < PG) ? PP - p0 : PG;
    hipMemsetAsync(hdr + OFF_S2SUM, 0, 8192 * sizeof(float), stream);
    k2_gemm2<<<dim3(NB / 128, H2C / 128, pg), 256, 0, stream>>>(h1a, W7b, b7,
                                                                hdr, h2b, p0);
    k3_fin<<<(pg * H2C + 255) / 256, 256, 0, stream>>>(g7, be7, hdr, p0, pg);
    kfold_w<<<pg * 56, 256, 0, stream>>>(W8, hdr, W8s, p0);
    kfold_b<<<pg * 56, 256, 0, stream>>>(W8, b8, hdr, p0);
    k4_gemm3<<<dim3(NB / 128, 1, pg), 256, 0, stream>>>(h2b, W8s, hdr, out, p0);
  }
}

// Round 6
// 426.115 us; speedup vs baseline: 1.1046x; 1.1046x over previous
//
#include <hip/hip_runtime.h>

#define PP 8
#define ZD 16
#define H1C 128
#define H2C 512
#define CHC 224
#define NB 32768
#define EPSV 1e-5f

// header layout in d_ws (float offsets)
#define OFF_S1SUM 0
#define OFF_S1SQ  1024
#define OFF_SC1   2048
#define OFF_SH1   3072
#define OFF_S2SUM 4096
#define OFF_S2SQ  8192
#define OFF_SC2F  12288
#define OFF_SH2F  16384
#define OFF_B8P   20480
#define OFF_TTH   22528
#define HDR_BYTES 131072

typedef __attribute__((ext_vector_type(8))) short s16x8;
typedef __attribute__((ext_vector_type(4))) float f32x4;

__device__ __forceinline__ unsigned short f2bf(float f) {
  unsigned int u = __float_as_uint(f);
  unsigned int r = (u + 0x7fffu + ((u >> 16) & 1u)) >> 16;
  return (unsigned short)r;
}
__device__ __forceinline__ float bf2f(unsigned short h) {
  return __uint_as_float((unsigned int)h << 16);
}

// async global->LDS, 16B per lane; lds dest is wave-uniform base + lane*16
#define GLL16(g, l)                                                        \
  __builtin_amdgcn_global_load_lds(                                        \
      (const __attribute__((address_space(1))) unsigned int*)(g),          \
      (__attribute__((address_space(3))) unsigned int*)(l), 16, 0, 0)

// ---------------------------------------------------------------------------
// kw: convert W7 -> W7b bf16, slot-swizzled by (c&7) within each 64-k chunk.
__global__ __launch_bounds__(256) void kw_conv(const float* __restrict__ W7,
                                               unsigned short* __restrict__ W7b) {
  int i8 = (blockIdx.x * 256 + threadIdx.x) * 8;
  int k = i8 & (H1C - 1);
  int c = (i8 >> 7) & (H2C - 1);
  int base = i8 - k;
  int kd = (k & ~63) + ((((k >> 3) & 7) ^ (c & 7)) << 3);
  float4 v0 = *(const float4*)&W7[i8];
  float4 v1 = *(const float4*)&W7[i8 + 4];
  s16x8 o;
  o[0] = (short)f2bf(v0.x); o[1] = (short)f2bf(v0.y);
  o[2] = (short)f2bf(v0.z); o[3] = (short)f2bf(v0.w);
  o[4] = (short)f2bf(v1.x); o[5] = (short)f2bf(v1.y);
  o[6] = (short)f2bf(v1.z); o[7] = (short)f2bf(v1.w);
  *(s16x8*)&W7b[base + kd] = o;
}

// ---------------------------------------------------------------------------
// K1: BN1 stats (fp32 h1 recompute from z, K=16)
__global__ __launch_bounds__(128) void k1_stats1(
    const float* __restrict__ z, const float* __restrict__ W6,
    const float* __restrict__ b6, float* __restrict__ hdr) {
  __shared__ float zs[512 * ZD];
  __shared__ float w6s[H1C * ZD];
  const int t = threadIdx.x;
  const int p = blockIdx.y;
  const int n0 = blockIdx.x * 512;
  for (int i = t; i < H1C * ZD; i += 128) w6s[i] = W6[(size_t)p * (H1C * ZD) + i];
  for (int i = t; i < 512 * ZD; i += 128) zs[i] = z[(size_t)n0 * ZD + i];
  __syncthreads();
  float wr_[ZD];
#pragma unroll
  for (int q = 0; q < ZD; ++q) wr_[q] = w6s[t * ZD + q];
  float bb = b6[p * H1C + t];
  float s = 0.f, sq = 0.f;
  for (int n = 0; n < 512; ++n) {
    float v = bb;
    const float4* zp = (const float4*)&zs[n * ZD];
#pragma unroll
    for (int q4 = 0; q4 < 4; ++q4) {
      float4 zv = zp[q4];
      v = fmaf(zv.x, wr_[q4 * 4 + 0], v);
      v = fmaf(zv.y, wr_[q4 * 4 + 1], v);
      v = fmaf(zv.z, wr_[q4 * 4 + 2], v);
      v = fmaf(zv.w, wr_[q4 * 4 + 3], v);
    }
    s += v;
    sq = fmaf(v, v, sq);
  }
  atomicAdd(&hdr[OFF_S1SUM + p * H1C + t], s);
  atomicAdd(&hdr[OFF_S1SQ + p * H1C + t], sq);
}

__global__ void k1_fin(const float* __restrict__ g6,
                       const float* __restrict__ be6, float* __restrict__ hdr) {
  int j = blockIdx.x * 256 + threadIdx.x;
  if (j >= PP * H1C) return;
  float mu = hdr[OFF_S1SUM + j] * (1.f / NB);
  float var = fmaxf(hdr[OFF_S1SQ + j] * (1.f / NB) - mu * mu, 0.f);
  float sc = g6[j] * rsqrtf(var + EPSV);
  hdr[OFF_SC1 + j] = sc;
  hdr[OFF_SH1 + j] = be6[j] - mu * sc;
}

// ---------------------------------------------------------------------------
// K1c: h1act = relu(affine(z*W6^T)) bf16 [p][n][128], slot-swizzled by n&7
__global__ __launch_bounds__(256) void k1c_act1(
    const float* __restrict__ z, const float* __restrict__ W6,
    const float* __restrict__ b6, const float* __restrict__ hdr,
    unsigned short* __restrict__ h1a) {
  __shared__ float w6s[H1C * 20];
  __shared__ float cb[H1C], cs[H1C], ch[H1C];
  const int t = threadIdx.x;
  const int p = blockIdx.y;
  const int n0 = blockIdx.x * 128;
  for (int i = t; i < H1C * ZD; i += 256)
    w6s[(i >> 4) * 20 + (i & 15)] = W6[(size_t)p * (H1C * ZD) + i];
  if (t < H1C) {
    cb[t] = b6[p * H1C + t];
    cs[t] = hdr[OFF_SC1 + p * H1C + t];
    ch[t] = hdr[OFF_SH1 + p * H1C + t];
  }
  __syncthreads();
  const int row = t >> 1;
  const int n = n0 + row;
  const int h0 = (t & 1) * 64;
  const float* zp = z + (size_t)n * ZD;
  float zr[ZD];
#pragma unroll
  for (int q = 0; q < ZD; ++q) zr[q] = zp[q];
  unsigned short* rowp = h1a + ((size_t)p * NB + n) * H1C;
  for (int hb = 0; hb < 64; hb += 8) {
    s16x8 o;
#pragma unroll
    for (int j = 0; j < 8; ++j) {
      int h = h0 + hb + j;
      float v = cb[h];
#pragma unroll
      for (int q4 = 0; q4 < 4; ++q4) {
        float4 wv = *(const float4*)&w6s[h * 20 + q4 * 4];
        v = fmaf(zr[q4 * 4 + 0], wv.x, v);
        v = fmaf(zr[q4 * 4 + 1], wv.y, v);
        v = fmaf(zr[q4 * 4 + 2], wv.z, v);
        v = fmaf(zr[q4 * 4 + 3], wv.w, v);
      }
      v = fmaxf(fmaf(v, cs[h], ch[h]), 0.f);
      o[j] = (short)f2bf(v);
    }
    int hbase = h0 + hb;
    int kd = (hbase & ~63) + ((((hbase >> 3) & 7) ^ (n & 7)) << 3);
    *(s16x8*)(rowp + kd) = o;
  }
}

// ---------------------------------------------------------------------------
// K2: bf16 MFMA GEMM (M=NB, N=512, K=128), fused bias + BN2 stats epilogue.
__global__ __launch_bounds__(256) void k2_gemm2(
    const unsigned short* __restrict__ h1a, const unsigned short* __restrict__ W7b,
    const float* __restrict__ b7, float* __restrict__ hdr,
    unsigned short* __restrict__ h2b, int p0) {
  __shared__ unsigned short Abuf[128 * 64];
  __shared__ unsigned short Bbuf[128 * 64];
  const int t = threadIdx.x;
  const int lane = t & 63;
  const int w = t >> 6, wr = w >> 1, wc = w & 1;
  const int pl = blockIdx.z, p = p0 + pl;
  const int n0 = blockIdx.x * 128;
  const int c0 = blockIdx.y * 128;

  const int srow = lane >> 3;
  const int ke = (lane & 7) * 8;
  const size_t abase = ((size_t)p * NB + n0) * H1C;
  const size_t bbase = ((size_t)p * H2C + c0) * H1C;

  f32x4 acc[4][4] = {};

  for (int kt = 0; kt < H1C / 64; ++kt) {
    __syncthreads();
#pragma unroll
    for (int c = 0; c < 4; ++c) {
      int row = (w * 4 + c) * 8 + srow;
      GLL16(h1a + abase + (size_t)row * H1C + kt * 64 + ke,
            (char*)Abuf + (w * 4 + c) * 1024);
      GLL16(W7b + bbase + (size_t)row * H1C + kt * 64 + ke,
            (char*)Bbuf + (w * 4 + c) * 1024);
    }
    __syncthreads();
    const int sw = lane & 7;
#pragma unroll
    for (int kk = 0; kk < 2; ++kk) {
      const int sl = kk * 4 + (lane >> 4);
      s16x8 af[4], bfv[4];
#pragma unroll
      for (int m = 0; m < 4; ++m)
        af[m] = *(const s16x8*)&Abuf[(wr * 64 + m * 16 + (lane & 15)) * 64 +
                                     ((sl ^ sw) << 3)];
#pragma unroll
      for (int n = 0; n < 4; ++n)
        bfv[n] = *(const s16x8*)&Bbuf[(wc * 64 + n * 16 + (lane & 15)) * 64 +
                                      ((sl ^ sw) << 3)];
#pragma unroll
      for (int m = 0; m < 4; ++m)
#pragma unroll
        for (int n = 0; n < 4; ++n)
          acc[m][n] = __builtin_amdgcn_mfma_f32_16x16x32_bf16(af[m], bfv[n],
                                                              acc[m][n], 0, 0, 0);
    }
  }

#pragma unroll
  for (int n = 0; n < 4; ++n) {
    const int col = c0 + wc * 64 + n * 16 + (lane & 15);
    const float bias = b7[p * H2C + col];
    float s = 0.f, q = 0.f;
#pragma unroll
    for (int m = 0; m < 4; ++m) {
      const int rowb = n0 + wr * 64 + m * 16 + (lane >> 4) * 4;
#pragma unroll
      for (int r = 0; r < 4; ++r) {
        float v = acc[m][n][r] + bias;
        unsigned short hb = f2bf(v);
        h2b[((size_t)pl * NB + rowb + r) * H2C + col] = hb;
        float vf = bf2f(hb);
        s += vf;
        q = fmaf(vf, vf, q);
      }
    }
    s += __shfl_xor(s, 16); q += __shfl_xor(q, 16);
    s += __shfl_xor(s, 32); q += __shfl_xor(q, 32);
    if ((lane >> 4) == 0) {
      atomicAdd(&hdr[OFF_S2SUM + p * H2C + col], s);
      atomicAdd(&hdr[OFF_S2SQ + p * H2C + col], q);
    }
  }
}

// K3fin: BN2 affine params -> flat sc, sh, and threshold t = -sh/sc
__global__ void k3_fin(const float* __restrict__ g7,
                       const float* __restrict__ be7, float* __restrict__ hdr,
                       int p0, int pg) {
  int idx = blockIdx.x * 256 + threadIdx.x;
  if (idx >= pg * H2C) return;
  int row = p0 * H2C + idx;
  float mu = hdr[OFF_S2SUM + row] * (1.f / NB);
  float var = fmaxf(hdr[OFF_S2SQ + row] * (1.f / NB) - mu * mu, 0.f);
  float sc = g7[row] * rsqrtf(var + EPSV);
  float sh = be7[row] - mu * sc;
  hdr[OFF_SC2F + row] = sc;
  hdr[OFF_SH2F + row] = sh;
  hdr[OFF_TTH + row] = -sh / sc;
}

// kfold_w: W8s[c,k] = bf16(W8[c,k] * sc[k]), slot-swizzled by (c&7)
__global__ __launch_bounds__(256) void kfold_w(const float* __restrict__ W8,
                                               const float* __restrict__ hdr,
                                               unsigned short* __restrict__ W8s,
                                               int p0) {
  int d = (blockIdx.x * 256 + threadIdx.x) * 8;  // within p-group
  int ks = d & (H2C - 1);
  int cc = d >> 9;
  int c = cc % CHC;
  int p = p0 + cc / CHC;
  int kl = (ks & ~63) + (((((ks >> 3) & 7)) ^ (c & 7)) << 3);
  const float* src = &W8[((size_t)p * CHC + c) * H2C + kl];
  const float* scp = &hdr[OFF_SC2F + p * H2C + kl];
  float4 v0 = *(const float4*)src, v1 = *(const float4*)(src + 4);
  float4 s0 = *(const float4*)scp, s1 = *(const float4*)(scp + 4);
  s16x8 o;
  o[0] = (short)f2bf(v0.x * s0.x); o[1] = (short)f2bf(v0.y * s0.y);
  o[2] = (short)f2bf(v0.z * s0.z); o[3] = (short)f2bf(v0.w * s0.w);
  o[4] = (short)f2bf(v1.x * s1.x); o[5] = (short)f2bf(v1.y * s1.y);
  o[6] = (short)f2bf(v1.z * s1.z); o[7] = (short)f2bf(v1.w * s1.w);
  *(s16x8*)&W8s[((size_t)p * CHC + c) * H2C + ks] = o;
}

// kfold_b: b8'[p,c] = b8[p,c] + sum_k W8[c,k]*sh[k]  (one wave per row)
__global__ __launch_bounds__(256) void kfold_b(const float* __restrict__ W8,
                                               const float* __restrict__ b8,
                                               float* __restrict__ hdr, int p0) {
  int gw = (blockIdx.x * 256 + threadIdx.x) >> 6;
  int lane = threadIdx.x & 63;
  int p = p0 + gw / CHC;
  int c = gw % CHC;
  const float* wrow = W8 + ((size_t)p * CHC + c) * H2C + lane * 8;
  const float* shp = hdr + OFF_SH2F + p * H2C + lane * 8;
  float s = 0.f;
  float4 a0 = *(const float4*)wrow, a1 = *(const float4*)(wrow + 4);
  float4 h0 = *(const float4*)shp, h1 = *(const float4*)(shp + 4);
  s = fmaf(a0.x, h0.x, s); s = fmaf(a0.y, h0.y, s);
  s = fmaf(a0.z, h0.z, s); s = fmaf(a0.w, h0.w, s);
  s = fmaf(a1.x, h1.x, s); s = fmaf(a1.y, h1.y, s);
  s = fmaf(a1.z, h1.z, s); s = fmaf(a1.w, h1.w, s);
  s += __shfl_xor(s, 1);  s += __shfl_xor(s, 2);  s += __shfl_xor(s, 4);
  s += __shfl_xor(s, 8);  s += __shfl_xor(s, 16); s += __shfl_xor(s, 32);
  if (lane == 0) hdr[OFF_B8P + p * CHC + c] = b8[p * CHC + c] + s;
}

// ---------------------------------------------------------------------------
// K4: bf16 MFMA GEMM (M=NB, N=224, K=512), 128x224 tile, 2 blocks/CU.
// A: reg-staged with cross-phase prefetch (issued after barrier2, drained at
// next barrier1); transform = max(v, t_k) only (BN folded into W8s/b8').
__global__ __launch_bounds__(256, 2) void k4_gemm3(
    const unsigned short* __restrict__ h2b, const unsigned short* __restrict__ W8s,
    const float* __restrict__ hdr, float* __restrict__ out, int p0) {
  __shared__ unsigned short Abuf[128 * 64];  // 16KB, slot-swizzled by row&7
  __shared__ unsigned short Bbuf[224 * 64];  // 28KB, swizzled via global layout
  __shared__ float tb[H2C];                  // 2KB thresholds
  const int t = threadIdx.x;
  const int lane = t & 63;
  const int w = t >> 6, wr = w >> 1, wc = w & 1;
  const int pl = blockIdx.z, p = p0 + pl;
  const int n0 = blockIdx.x * 128;

  for (int i = t; i < H2C; i += 256) tb[i] = hdr[OFF_TTH + p * H2C + i];

  const int r = t >> 1;
  const int sb = (t & 1) * 4;
  const unsigned short* arow = h2b + ((size_t)pl * NB + n0 + r) * H2C + sb * 8;
  const int qrow = lane >> 3, qsl = lane & 7;

  f32x4 acc[4][7] = {};
  s16x8 cur[4], nxt[4];
#pragma unroll
  for (int j = 0; j < 4; ++j) cur[j] = *(const s16x8*)(arow + j * 8);

  for (int kt = 0; kt < H2C / 64; ++kt) {
    __syncthreads();  // drains prefetched A(kt) + prev frag reads; tb at kt=0
    // B staging: 28 one-KB blocks (8 rows x 64 k each); 4 waves x 7
#pragma unroll
    for (int c = 0; c < 7; ++c) {
      int qq = w * 7 + c;
      GLL16(W8s + ((size_t)p * CHC + qq * 8 + qrow) * H2C + kt * 64 + qsl * 8,
            (char*)Bbuf + qq * 1024);
    }
    // transform cur -> Abuf: A' = max(v, t_k); pack via v_cvt_pk_bf16_f32
#pragma unroll
    for (int j = 0; j < 4; ++j) {
      int kb = kt * 64 + sb * 8 + j * 8;
      f32x4 t0 = *(const f32x4*)&tb[kb];
      f32x4 t1 = *(const f32x4*)&tb[kb + 4];
      float m0 = fmaxf(bf2f((unsigned short)cur[j][0]), t0[0]);
      float m1 = fmaxf(bf2f((unsigned short)cur[j][1]), t0[1]);
      float m2 = fmaxf(bf2f((unsigned short)cur[j][2]), t0[2]);
      float m3 = fmaxf(bf2f((unsigned short)cur[j][3]), t0[3]);
      float m4 = fmaxf(bf2f((unsigned short)cur[j][4]), t1[0]);
      float m5 = fmaxf(bf2f((unsigned short)cur[j][5]), t1[1]);
      float m6 = fmaxf(bf2f((unsigned short)cur[j][6]), t1[2]);
      float m7 = fmaxf(bf2f((unsigned short)cur[j][7]), t1[3]);
      unsigned int w0, w1, w2, w3;
      asm("v_cvt_pk_bf16_f32 %0, %1, %2" : "=v"(w0) : "v"(m0), "v"(m1));
      asm("v_cvt_pk_bf16_f32 %0, %1, %2" : "=v"(w1) : "v"(m2), "v"(m3));
      asm("v_cvt_pk_bf16_f32 %0, %1, %2" : "=v"(w2) : "v"(m4), "v"(m5));
      asm("v_cvt_pk_bf16_f32 %0, %1, %2" : "=v"(w3) : "v"(m6), "v"(m7));
      uint4 o;
      o.x = w0; o.y = w1; o.z = w2; o.w = w3;
      int slot = (sb + j) ^ (r & 7);
      *(uint4*)((char*)Abuf + r * 128 + slot * 16) = o;
    }
    __syncthreads();
    // prefetch A for kt+1: latency overlaps the MFMA region below,
    // drained at next iteration's barrier1, used right after it.
    if (kt < 7) {
#pragma unroll
      for (int j = 0; j < 4; ++j)
        nxt[j] = *(const s16x8*)(arow + (kt + 1) * 64 + j * 8);
    }
    const int sw = lane & 7;
#pragma unroll
    for (int kk = 0; kk < 2; ++kk) {
      const int sl = kk * 4 + (lane >> 4);
      s16x8 af[4], bfv[7];
#pragma unroll
      for (int m = 0; m < 4; ++m)
        af[m] = *(const s16x8*)&Abuf[(wr * 64 + m * 16 + (lane & 15)) * 64 +
                                     ((sl ^ sw) << 3)];
#pragma unroll
      for (int n = 0; n < 7; ++n)
        bfv[n] = *(const s16x8*)&Bbuf[(wc * 112 + n * 16 + (lane & 15)) * 64 +
                                      ((sl ^ sw) << 3)];
#pragma unroll
      for (int m = 0; m < 4; ++m)
#pragma unroll
        for (int n = 0; n < 7; ++n)
          acc[m][n] = __builtin_amdgcn_mfma_f32_16x16x32_bf16(af[m], bfv[n],
                                                              acc[m][n], 0, 0, 0);
    }
    if (kt < 7) {
#pragma unroll
      for (int j = 0; j < 4; ++j) cur[j] = nxt[j];
    }
  }

#pragma unroll
  for (int n = 0; n < 7; ++n) {
    const int col = wc * 112 + n * 16 + (lane & 15);
    const float bias = hdr[OFF_B8P + p * CHC + col];
#pragma unroll
    for (int m = 0; m < 4; ++m) {
      const int rowb = n0 + wr * 64 + m * 16 + (lane >> 4) * 4;
#pragma unroll
      for (int rr = 0; rr < 4; ++rr) {
        float x = acc[m][n][rr] + bias;
        out[((size_t)(rowb + rr) * PP + p) * CHC + col] = 1.f / (1.f + __expf(-x));
      }
    }
  }
}

// ---------------------------------------------------------------------------
extern "C" void kernel_launch(void* const* d_in, const int* in_sizes, int n_in,
                              void* d_out, int out_size, void* d_ws,
                              size_t ws_size, hipStream_t stream) {
  (void)in_sizes; (void)n_in; (void)out_size;
  const float* z   = (const float*)d_in[0];
  const float* W6  = (const float*)d_in[1];
  const float* b6  = (const float*)d_in[2];
  const float* g6  = (const float*)d_in[3];
  const float* be6 = (const float*)d_in[4];
  const float* W7  = (const float*)d_in[5];
  const float* b7  = (const float*)d_in[6];
  const float* g7  = (const float*)d_in[7];
  const float* be7 = (const float*)d_in[8];
  const float* W8  = (const float*)d_in[9];
  const float* b8  = (const float*)d_in[10];
  float* out = (float*)d_out;
  float* hdr = (float*)d_ws;
  unsigned short* W7b = (unsigned short*)((char*)d_ws + HDR_BYTES);
  unsigned short* W8s = W7b + (size_t)PP * H2C * H1C;
  unsigned short* h1a = W8s + (size_t)PP * CHC * H2C;
  unsigned short* h2b = h1a + (size_t)PP * NB * H1C;

  size_t fixed = HDR_BYTES + 2 * ((size_t)PP * H2C * H1C + (size_t)PP * CHC * H2C +
                                  (size_t)PP * NB * H1C);
  size_t per_p = (size_t)NB * H2C * 2;
  size_t avail = ws_size > fixed ? ws_size - fixed : 0;
  int PG = (int)(avail / per_p);
  if (PG < 1) PG = 1;
  if (PG > PP) PG = PP;

  hipMemsetAsync(hdr + OFF_S1SUM, 0, 2048 * sizeof(float), stream);
  kw_conv<<<256, 256, 0, stream>>>(W7, W7b);
  k1_stats1<<<dim3(NB / 512, PP), 128, 0, stream>>>(z, W6, b6, hdr);
  k1_fin<<<4, 256, 0, stream>>>(g6, be6, hdr);
  k1c_act1<<<dim3(NB / 128, PP), 256, 0, stream>>>(z, W6, b6, hdr, h1a);

  for (int p0 = 0; p0 < PP; p0 += PG) {
    int pg = (PP - p0 < PG) ? PP - p0 : PG;
    hipMemsetAsync(hdr + OFF_S2SUM, 0, 8192 * sizeof(float), stream);
    k2_gemm2<<<dim3(NB / 128, H2C / 128, pg), 256, 0, stream>>>(h1a, W7b, b7,
                                                                hdr, h2b, p0);
    k3_fin<<<(pg * H2C + 255) / 256, 256, 0, stream>>>(g7, be7, hdr, p0, pg);
    kfold_w<<<pg * 56, 256, 0, stream>>>(W8, hdr, W8s, p0);
    kfold_b<<<pg * 56, 256, 0, stream>>>(W8, b8, hdr, p0);
    k4_gemm3<<<dim3(NB / 128, 1, pg), 256, 0, stream>>>(h2b, W8s, hdr, out, p0);
  }
}